// Round 1
// baseline (25445.251 us; speedup 1.0000x reference)
//
#include <hip/hip_runtime.h>
#include <math.h>

#define VCAB 80
#define EDIM 8
#define HDIM 256
#define BAT 2048
#define SEQ 256
#define BT 8            // batch rows per workgroup
#define NWG (BAT/BT)    // 256 workgroups

// ws layout (floats)
#define W0T_K 264                 // E + H
#define W1T_K 512                 // H + H
#define W0T_OFF 0
#define W1T_OFF (W0T_K*1024)              // 270336
#define BIAS0_OFF (W1T_OFF + W1T_K*1024)  // 794624
#define BIAS1_OFF (BIAS0_OFF + 1024)
#define WS_FLOATS (BIAS1_OFF + 1024)      // 796672 floats ~ 3.04 MB

// Pre-transpose weights into gate-interleaved layout:
// WT[k][unit*4+g] = W[g*H+unit][k]  (g in {i,f,g,o} order, PyTorch LSTM order)
// so each thread's float4 load at [k*1024 + 4*tid] yields (i,f,g,o) of unit `tid`.
__global__ void prep_kernel(const float* __restrict__ Wih0, const float* __restrict__ Whh0,
                            const float* __restrict__ bih0, const float* __restrict__ bhh0,
                            const float* __restrict__ Wih1, const float* __restrict__ Whh1,
                            const float* __restrict__ bih1, const float* __restrict__ bhh1,
                            float* __restrict__ ws) {
  int idx = blockIdx.x * 256 + threadIdx.x;
  if (idx < W0T_K * 1024) {
    int k = idx >> 10, n2 = idx & 1023;
    int unit = n2 >> 2, g = n2 & 3, r = g * HDIM + unit;
    float v = (k < EDIM) ? Wih0[r * EDIM + k] : Whh0[r * HDIM + (k - EDIM)];
    ws[W0T_OFF + idx] = v;
  } else if (idx < W0T_K * 1024 + W1T_K * 1024) {
    int i2 = idx - W0T_K * 1024;
    int k = i2 >> 10, n2 = i2 & 1023;
    int unit = n2 >> 2, g = n2 & 3, r = g * HDIM + unit;
    float v = (k < HDIM) ? Wih1[r * HDIM + k] : Whh1[r * HDIM + (k - HDIM)];
    ws[W1T_OFF + i2] = v;
  } else if (idx < W0T_K * 1024 + W1T_K * 1024 + 1024) {
    int n2 = idx - (W0T_K * 1024 + W1T_K * 1024);
    int unit = n2 >> 2, g = n2 & 3, r = g * HDIM + unit;
    ws[BIAS0_OFF + n2] = bih0[r] + bhh0[r];
  } else if (idx < W0T_K * 1024 + W1T_K * 1024 + 2048) {
    int n2 = idx - (W0T_K * 1024 + W1T_K * 1024 + 1024);
    int unit = n2 >> 2, g = n2 & 3, r = g * HDIM + unit;
    ws[BIAS1_OFF + n2] = bih1[r] + bhh1[r];
  }
}

__device__ __forceinline__ float sigm(float x) {
  return 1.0f / (1.0f + __expf(-x));
}
__device__ __forceinline__ float tanh_f(float x) {
  float ax = fabsf(x);
  float e = __expf(-2.0f * ax);
  float t = 1.0f - 2.0f * e / (1.0f + e);
  return copysignf(t, x);
}

// One workgroup owns BT=8 batch rows for the entire sequence. Thread tid owns
// hidden unit `tid` (all 4 gates, all 8 rows). No inter-block sync needed.
__global__ __launch_bounds__(256) void lstm_kernel(
    const int* __restrict__ x, const float* __restrict__ emb,
    const float* __restrict__ ws,
    const float* __restrict__ fcw, const float* __restrict__ fcb,
    float* __restrict__ out) {
  __shared__ float inp0[BT][W0T_K];  // [e(8) | h0(256)] per row
  __shared__ float inp1[BT][W1T_K];  // [h0new(256) | h1(256)] per row

  const int tid = threadIdx.x;
  const int bg = blockIdx.x * BT;
  const float4* __restrict__ W0 = (const float4*)(ws + W0T_OFF);
  const float4* __restrict__ W1 = (const float4*)(ws + W1T_OFF);

  float c0[BT], c1[BT];
#pragma unroll
  for (int b = 0; b < BT; b++) {
    c0[b] = 0.f; c1[b] = 0.f;
    inp0[b][EDIM + tid] = 0.f;
    inp1[b][tid] = 0.f;
    inp1[b][HDIM + tid] = 0.f;
  }
  const float4 bias0 = ((const float4*)(ws + BIAS0_OFF))[tid];
  const float4 bias1 = ((const float4*)(ws + BIAS1_OFF))[tid];
  __syncthreads();

  for (int t = 0; t < SEQ; t++) {
    // stage embeddings for this step: inp0[b][0..7]
    if (tid < BT * EDIM) {
      int b = tid >> 3, d = tid & 7;
      int xv = x[(bg + b) * SEQ + t];
      inp0[b][d] = emb[xv * EDIM + d];
    }
    __syncthreads();

    // ---- layer 0 gates: [BT x 1024] = inp0[BT x 264] @ W0T ----
    float4 acc[BT];
#pragma unroll
    for (int b = 0; b < BT; b++) acc[b] = bias0;
#pragma unroll 2
    for (int k4 = 0; k4 < W0T_K / 4; k4++) {
      float4 wa = W0[(4 * k4 + 0) * 256 + tid];
      float4 wb = W0[(4 * k4 + 1) * 256 + tid];
      float4 wc = W0[(4 * k4 + 2) * 256 + tid];
      float4 wd = W0[(4 * k4 + 3) * 256 + tid];
#pragma unroll
      for (int b = 0; b < BT; b++) {
        float4 hv = *(const float4*)&inp0[b][4 * k4];
        acc[b].x += hv.x * wa.x; acc[b].y += hv.x * wa.y; acc[b].z += hv.x * wa.z; acc[b].w += hv.x * wa.w;
        acc[b].x += hv.y * wb.x; acc[b].y += hv.y * wb.y; acc[b].z += hv.y * wb.z; acc[b].w += hv.y * wb.w;
        acc[b].x += hv.z * wc.x; acc[b].y += hv.z * wc.y; acc[b].z += hv.z * wc.z; acc[b].w += hv.z * wc.w;
        acc[b].x += hv.w * wd.x; acc[b].y += hv.w * wd.y; acc[b].z += hv.w * wd.z; acc[b].w += hv.w * wd.w;
      }
    }
    float h0n[BT];
#pragma unroll
    for (int b = 0; b < BT; b++) {
      float ig = sigm(acc[b].x), fg = sigm(acc[b].y);
      float gg = tanh_f(acc[b].z), og = sigm(acc[b].w);
      c0[b] = fg * c0[b] + ig * gg;
      h0n[b] = og * tanh_f(c0[b]);
    }
    __syncthreads();  // all waves done reading inp0 before overwrite
#pragma unroll
    for (int b = 0; b < BT; b++) {
      inp0[b][EDIM + tid] = h0n[b];  // h0 input for next step
      inp1[b][tid] = h0n[b];         // layer-1 input this step
    }
    __syncthreads();

    // ---- layer 1 gates: [BT x 1024] = inp1[BT x 512] @ W1T ----
#pragma unroll
    for (int b = 0; b < BT; b++) acc[b] = bias1;
#pragma unroll 2
    for (int k4 = 0; k4 < W1T_K / 4; k4++) {
      float4 wa = W1[(4 * k4 + 0) * 256 + tid];
      float4 wb = W1[(4 * k4 + 1) * 256 + tid];
      float4 wc = W1[(4 * k4 + 2) * 256 + tid];
      float4 wd = W1[(4 * k4 + 3) * 256 + tid];
#pragma unroll
      for (int b = 0; b < BT; b++) {
        float4 hv = *(const float4*)&inp1[b][4 * k4];
        acc[b].x += hv.x * wa.x; acc[b].y += hv.x * wa.y; acc[b].z += hv.x * wa.z; acc[b].w += hv.x * wa.w;
        acc[b].x += hv.y * wb.x; acc[b].y += hv.y * wb.y; acc[b].z += hv.y * wb.z; acc[b].w += hv.y * wb.w;
        acc[b].x += hv.z * wc.x; acc[b].y += hv.z * wc.y; acc[b].z += hv.z * wc.z; acc[b].w += hv.z * wc.w;
        acc[b].x += hv.w * wd.x; acc[b].y += hv.w * wd.y; acc[b].z += hv.w * wd.z; acc[b].w += hv.w * wd.w;
      }
    }
    float h1n[BT];
#pragma unroll
    for (int b = 0; b < BT; b++) {
      float ig = sigm(acc[b].x), fg = sigm(acc[b].y);
      float gg = tanh_f(acc[b].z), og = sigm(acc[b].w);
      c1[b] = fg * c1[b] + ig * gg;
      h1n[b] = og * tanh_f(c1[b]);
    }
    __syncthreads();  // all waves done reading inp1 before overwrite
#pragma unroll
    for (int b = 0; b < BT; b++) inp1[b][HDIM + tid] = h1n[b];
    // next iteration's barriers cover the write->read hazard for inp1
  }
  __syncthreads();

  // ---- FC: logits[bg+b][v] = h1[b] . fcw[v] + fcb[v] ----
  for (int o = tid; o < BT * VCAB; o += 256) {
    int b = o / VCAB, v = o - b * VCAB;
    float a = fcb[v];
    const float4* wrow = (const float4*)(fcw + v * HDIM);
    const float4* hrow = (const float4*)&inp1[b][HDIM];
#pragma unroll 4
    for (int k = 0; k < HDIM / 4; k++) {
      float4 w = wrow[k];
      float4 h = hrow[k];
      a += h.x * w.x + h.y * w.y + h.z * w.z + h.w * w.w;
    }
    out[(bg + b) * VCAB + v] = a;
  }

  // ---- final h, c states: out layout = [logits | h(2,B,H) | c(2,B,H)] ----
  float* outh = out + BAT * VCAB;
  float* outc = outh + 2 * BAT * HDIM;
#pragma unroll
  for (int b = 0; b < BT; b++) {
    outh[0 * BAT * HDIM + (bg + b) * HDIM + tid] = inp0[b][EDIM + tid];
    outh[1 * BAT * HDIM + (bg + b) * HDIM + tid] = inp1[b][HDIM + tid];
    outc[0 * BAT * HDIM + (bg + b) * HDIM + tid] = c0[b];
    outc[1 * BAT * HDIM + (bg + b) * HDIM + tid] = c1[b];
  }
}

extern "C" void kernel_launch(void* const* d_in, const int* in_sizes, int n_in,
                              void* d_out, int out_size, void* d_ws, size_t ws_size,
                              hipStream_t stream) {
  const int*   x    = (const int*)d_in[0];
  const float* emb  = (const float*)d_in[1];
  const float* Wih0 = (const float*)d_in[2];
  const float* Whh0 = (const float*)d_in[3];
  const float* bih0 = (const float*)d_in[4];
  const float* bhh0 = (const float*)d_in[5];
  const float* Wih1 = (const float*)d_in[6];
  const float* Whh1 = (const float*)d_in[7];
  const float* bih1 = (const float*)d_in[8];
  const float* bhh1 = (const float*)d_in[9];
  const float* fcw  = (const float*)d_in[10];
  const float* fcb  = (const float*)d_in[11];
  float* out = (float*)d_out;
  float* ws  = (float*)d_ws;

  prep_kernel<<<(WS_FLOATS + 255) / 256, 256, 0, stream>>>(
      Wih0, Whh0, bih0, bhh0, Wih1, Whh1, bih1, bhh1, ws);
  lstm_kernel<<<NWG, 256, 0, stream>>>(x, emb, ws, fcw, fcb, out);
}

// Round 5
// 14710.901 us; speedup vs baseline: 1.7297x; 1.7297x over previous
//
#include <hip/hip_runtime.h>
#include <math.h>

#define VCAB 80
#define EDIM 8
#define HDIM 256
#define BAT 2048
#define SEQ 256
#define BT 8            // batch rows per workgroup
#define NWG (BAT/BT)    // 256 workgroups
#define NTHR 512        // 2 K-split groups x 256

// ws layout (floats)
#define W0T_K 264                 // E + H
#define W1T_K 512                 // H + H
#define W0T_OFF 0
#define W1T_OFF (W0T_K*1024)              // 270336
#define BIAS0_OFF (W1T_OFF + W1T_K*1024)  // 794624
#define BIAS1_OFF (BIAS0_OFF + 1024)
#define WS_FLOATS (BIAS1_OFF + 1024)      // 796672 floats ~ 3.04 MB

// Pre-transpose weights into gate-interleaved layout:
// WT[k][unit*4+g] = W[g*H+unit][k]  (g in {i,f,g,o} order, PyTorch LSTM order)
// so each thread's float4 load at [k*1024 + 4*tid] yields (i,f,g,o) of unit `tid`.
__global__ void prep_kernel(const float* __restrict__ Wih0, const float* __restrict__ Whh0,
                            const float* __restrict__ bih0, const float* __restrict__ bhh0,
                            const float* __restrict__ Wih1, const float* __restrict__ Whh1,
                            const float* __restrict__ bih1, const float* __restrict__ bhh1,
                            float* __restrict__ ws) {
  int idx = blockIdx.x * 256 + threadIdx.x;
  if (idx < W0T_K * 1024) {
    int k = idx >> 10, n2 = idx & 1023;
    int unit = n2 >> 2, g = n2 & 3, r = g * HDIM + unit;
    float v = (k < EDIM) ? Wih0[r * EDIM + k] : Whh0[r * HDIM + (k - EDIM)];
    ws[W0T_OFF + idx] = v;
  } else if (idx < W0T_K * 1024 + W1T_K * 1024) {
    int i2 = idx - W0T_K * 1024;
    int k = i2 >> 10, n2 = i2 & 1023;
    int unit = n2 >> 2, g = n2 & 3, r = g * HDIM + unit;
    float v = (k < HDIM) ? Wih1[r * HDIM + k] : Whh1[r * HDIM + (k - HDIM)];
    ws[W1T_OFF + i2] = v;
  } else if (idx < W0T_K * 1024 + W1T_K * 1024 + 1024) {
    int n2 = idx - (W0T_K * 1024 + W1T_K * 1024);
    int unit = n2 >> 2, g = n2 & 3, r = g * HDIM + unit;
    ws[BIAS0_OFF + n2] = bih0[r] + bhh0[r];
  } else if (idx < W0T_K * 1024 + W1T_K * 1024 + 2048) {
    int n2 = idx - (W0T_K * 1024 + W1T_K * 1024 + 1024);
    int unit = n2 >> 2, g = n2 & 3, r = g * HDIM + unit;
    ws[BIAS1_OFF + n2] = bih1[r] + bhh1[r];
  }
}

__device__ __forceinline__ float sigm(float x) {
  return 1.0f / (1.0f + __expf(-x));
}
__device__ __forceinline__ float tanh_f(float x) {
  float ax = fabsf(x);
  float e = __expf(-2.0f * ax);
  float t = 1.0f - 2.0f * e / (1.0f + e);
  return copysignf(t, x);
}

#define FMA4(A, HS, W) \
  A.x += (HS) * (W).x; A.y += (HS) * (W).y; A.z += (HS) * (W).z; A.w += (HS) * (W).w;

// One workgroup owns BT=8 batch rows for the entire sequence.
// 512 threads = 2 K-split groups of 256. utid = unit index (owns 4 gates of
// that unit across all 8 rows); grp = which half of the reduction dim.
// Group 1 deposits partial sums in LDS; group 0 reduces + applies activations
// and owns the c-state registers. No inter-block sync anywhere.
__global__ __launch_bounds__(NTHR, 2) void lstm_kernel(
    const int* __restrict__ x, const float* __restrict__ emb,
    const float* __restrict__ ws,
    const float* __restrict__ fcw, const float* __restrict__ fcb,
    float* __restrict__ out) {
  __shared__ float inp0[BT][W0T_K];   // [e(8) | h0(256)] per row        8448 B
  __shared__ float inp1[BT][W1T_K];   // [h0new(256) | h1(256)] per row 16384 B
  __shared__ float4 red[BT][HDIM];    // group-1 partial gate sums      32768 B

  const int tid = threadIdx.x;
  const int grp = tid >> 8;       // 0 or 1
  const int utid = tid & 255;     // unit index
  const int bg = blockIdx.x * BT;
  const float4* __restrict__ W0 = (const float4*)(ws + W0T_OFF);
  const float4* __restrict__ W1 = (const float4*)(ws + W1T_OFF);

  float c0[BT], c1[BT];
#pragma unroll
  for (int b = 0; b < BT; b++) { c0[b] = 0.f; c1[b] = 0.f; }
  if (grp == 0) {
#pragma unroll
    for (int b = 0; b < BT; b++) {
      inp0[b][EDIM + utid] = 0.f;
      inp1[b][utid] = 0.f;
      inp1[b][HDIM + utid] = 0.f;
    }
  }
  const float4 bias0 = ((const float4*)(ws + BIAS0_OFF))[utid];
  const float4 bias1 = ((const float4*)(ws + BIAS1_OFF))[utid];
  __syncthreads();

  for (int t = 0; t < SEQ; t++) {
    // stage embeddings for this step: inp0[b][0..7]
    if (tid < BT * EDIM) {
      int b = tid >> 3, d = tid & 7;
      int xv = x[(bg + b) * SEQ + t];
      inp0[b][d] = emb[xv * EDIM + d];
    }
    __syncthreads();

    // ---- layer 0: gates[BT x 1024] = inp0[BT x 264] @ W0T, K split 132/132
    float4 acc[BT];
#pragma unroll
    for (int b = 0; b < BT; b++)
      acc[b] = (grp == 0) ? bias0 : make_float4(0.f, 0.f, 0.f, 0.f);
    {
      const int kbase = grp * (W0T_K / 2);   // 0 or 132
#pragma unroll 3
      for (int i = 0; i < W0T_K / 8; i++) {  // 33 iters of 4 k-steps
        const int k = kbase + 4 * i;
        float4 wa = W0[(k + 0) * 256 + utid];
        float4 wb = W0[(k + 1) * 256 + utid];
        float4 wc = W0[(k + 2) * 256 + utid];
        float4 wd = W0[(k + 3) * 256 + utid];
#pragma unroll
        for (int b = 0; b < BT; b++) {
          float4 hv = *(const float4*)&inp0[b][k];
          FMA4(acc[b], hv.x, wa); FMA4(acc[b], hv.y, wb);
          FMA4(acc[b], hv.z, wc); FMA4(acc[b], hv.w, wd);
        }
      }
    }
    if (grp == 1) {
#pragma unroll
      for (int b = 0; b < BT; b++) red[b][utid] = acc[b];
    }
    __syncthreads();   // partials visible; all inp0 reads complete
    if (grp == 0) {
#pragma unroll
      for (int b = 0; b < BT; b++) {
        float4 p = red[b][utid];
        float ig = sigm(acc[b].x + p.x), fg = sigm(acc[b].y + p.y);
        float gg = tanh_f(acc[b].z + p.z), og = sigm(acc[b].w + p.w);
        c0[b] = fg * c0[b] + ig * gg;
        float h = og * tanh_f(c0[b]);
        inp0[b][EDIM + utid] = h;   // h0 input for next step
        inp1[b][utid] = h;          // layer-1 input this step
      }
    }
    __syncthreads();   // h0new visible; red free for reuse

    // ---- layer 1: gates[BT x 1024] = inp1[BT x 512] @ W1T, K split 256/256
#pragma unroll
    for (int b = 0; b < BT; b++)
      acc[b] = (grp == 0) ? bias1 : make_float4(0.f, 0.f, 0.f, 0.f);
    {
      const int kbase = grp * (W1T_K / 2);   // 0 or 256
#pragma unroll 4
      for (int i = 0; i < W1T_K / 8; i++) {  // 64 iters of 4 k-steps
        const int k = kbase + 4 * i;
        float4 wa = W1[(k + 0) * 256 + utid];
        float4 wb = W1[(k + 1) * 256 + utid];
        float4 wc = W1[(k + 2) * 256 + utid];
        float4 wd = W1[(k + 3) * 256 + utid];
#pragma unroll
        for (int b = 0; b < BT; b++) {
          float4 hv = *(const float4*)&inp1[b][k];
          FMA4(acc[b], hv.x, wa); FMA4(acc[b], hv.y, wb);
          FMA4(acc[b], hv.z, wc); FMA4(acc[b], hv.w, wd);
        }
      }
    }
    if (grp == 1) {
#pragma unroll
      for (int b = 0; b < BT; b++) red[b][utid] = acc[b];
    }
    __syncthreads();   // partials visible; all inp1 reads complete
    if (grp == 0) {
#pragma unroll
      for (int b = 0; b < BT; b++) {
        float4 p = red[b][utid];
        float ig = sigm(acc[b].x + p.x), fg = sigm(acc[b].y + p.y);
        float gg = tanh_f(acc[b].z + p.z), og = sigm(acc[b].w + p.w);
        c1[b] = fg * c1[b] + ig * gg;
        inp1[b][HDIM + utid] = og * tanh_f(c1[b]);
      }
    }
    __syncthreads();   // h1new visible for next step's layer-1 / epilogue
  }

  // ---- FC: logits[bg+b][v] = h1[b] . fcw[v] + fcb[v] ----
  for (int o = tid; o < BT * VCAB; o += NTHR) {
    int b = o / VCAB, v = o - b * VCAB;
    float a = fcb[v];
    const float4* wrow = (const float4*)(fcw + v * HDIM);
    const float4* hrow = (const float4*)&inp1[b][HDIM];
#pragma unroll 4
    for (int k = 0; k < HDIM / 4; k++) {
      float4 w = wrow[k];
      float4 h = hrow[k];
      a += h.x * w.x + h.y * w.y + h.z * w.z + h.w * w.w;
    }
    out[(bg + b) * VCAB + v] = a;
  }

  // ---- final h, c states: out layout = [logits | h(2,B,H) | c(2,B,H)] ----
  // c0/c1 live only in group-0 registers.
  if (grp == 0) {
    float* outh = out + BAT * VCAB;
    float* outc = outh + 2 * BAT * HDIM;
#pragma unroll
    for (int b = 0; b < BT; b++) {
      outh[0 * BAT * HDIM + (bg + b) * HDIM + utid] = inp0[b][EDIM + utid];
      outh[1 * BAT * HDIM + (bg + b) * HDIM + utid] = inp1[b][HDIM + utid];
      outc[0 * BAT * HDIM + (bg + b) * HDIM + utid] = c0[b];
      outc[1 * BAT * HDIM + (bg + b) * HDIM + utid] = c1[b];
    }
  }
}

extern "C" void kernel_launch(void* const* d_in, const int* in_sizes, int n_in,
                              void* d_out, int out_size, void* d_ws, size_t ws_size,
                              hipStream_t stream) {
  const int*   x    = (const int*)d_in[0];
  const float* emb  = (const float*)d_in[1];
  const float* Wih0 = (const float*)d_in[2];
  const float* Whh0 = (const float*)d_in[3];
  const float* bih0 = (const float*)d_in[4];
  const float* bhh0 = (const float*)d_in[5];
  const float* Wih1 = (const float*)d_in[6];
  const float* Whh1 = (const float*)d_in[7];
  const float* bih1 = (const float*)d_in[8];
  const float* bhh1 = (const float*)d_in[9];
  const float* fcw  = (const float*)d_in[10];
  const float* fcb  = (const float*)d_in[11];
  float* out = (float*)d_out;
  float* ws  = (float*)d_ws;

  prep_kernel<<<(WS_FLOATS + 255) / 256, 256, 0, stream>>>(
      Wih0, Whh0, bih0, bhh0, Wih1, Whh1, bih1, bhh1, ws);
  lstm_kernel<<<NWG, NTHR, 0, stream>>>(x, emb, ws, fcw, fcb, out);
}